// Round 6
// baseline (4274.968 us; speedup 1.0000x reference)
//
#include <hip/hip_runtime.h>
#include <math.h>

#define VOCAB  32000
#define EMB    256
#define HID    512
#define MAXLEN 512
#define BATCH  128
#define NCLASS 2

#define NB_J    8    // column groups (64 cols each)
#define NB_B    32   // batch groups (4 rows each)
#define ROWS_PB 4
#define COLS_PB 64

// ---------------------------------------------------------------------------
// Kernel A: embW[v][j] = b_h[j] + sum_e emb[v][e] * W_ih[e][j]
// (unchanged — ~70 us)
// ---------------------------------------------------------------------------
__global__ __launch_bounds__(256, 1) void embw_kernel(
    const float* __restrict__ emb, const float* __restrict__ W_ih,
    const float* __restrict__ b_h, float* __restrict__ embW)
{
    __shared__ __align__(16) float aT[EMB][64];
    __shared__ __align__(16) float wS[32][HID];

    const int t    = threadIdx.x;
    const int row0 = blockIdx.x * 64;

    {
        const int row   = t >> 2;
        const int elane = t & 3;
        for (int i = 0; i < 16; ++i) {
            const int e = elane * 4 + i * 16;
            const float4 v = *reinterpret_cast<const float4*>(
                &emb[(size_t)(row0 + row) * EMB + e]);
            aT[e + 0][row] = v.x;
            aT[e + 1][row] = v.y;
            aT[e + 2][row] = v.z;
            aT[e + 3][row] = v.w;
        }
    }

    const int rg = t >> 5;
    const int cg = t & 31;

    float acc[8][16];
    #pragma unroll
    for (int r = 0; r < 8; ++r)
        #pragma unroll
        for (int c = 0; c < 16; ++c) acc[r][c] = 0.f;

    for (int ec = 0; ec < 8; ++ec) {
        __syncthreads();
        {
            const int j4  = (t & 127) * 4;
            const int keb = (t >> 7);
            #pragma unroll
            for (int i = 0; i < 16; ++i) {
                const int ke = keb + i * 2;
                const float4 v = *reinterpret_cast<const float4*>(
                    &W_ih[(size_t)(ec * 32 + ke) * HID + j4]);
                *reinterpret_cast<float4*>(&wS[ke][j4]) = v;
            }
        }
        __syncthreads();

        for (int ke = 0; ke < 32; ++ke) {
            float a8[8];
            *(float4*)&a8[0] = *(const float4*)&aT[ec * 32 + ke][rg * 8];
            *(float4*)&a8[4] = *(const float4*)&aT[ec * 32 + ke][rg * 8 + 4];
            float w16[16];
            #pragma unroll
            for (int q = 0; q < 4; ++q)
                *(float4*)&w16[q * 4] =
                    *(const float4*)&wS[ke][cg * 16 + q * 4];
            #pragma unroll
            for (int r = 0; r < 8; ++r)
                #pragma unroll
                for (int c = 0; c < 16; ++c)
                    acc[r][c] = fmaf(a8[r], w16[c], acc[r][c]);
        }
    }

    float bh[16];
    #pragma unroll
    for (int q = 0; q < 4; ++q)
        *(float4*)&bh[q * 4] = *(const float4*)&b_h[cg * 16 + q * 4];
    #pragma unroll
    for (int r = 0; r < 8; ++r) {
        const size_t orow = (size_t)(row0 + rg * 8 + r) * HID + cg * 16;
        #pragma unroll
        for (int q = 0; q < 4; ++q) {
            float4 v;
            v.x = acc[r][q * 4 + 0] + bh[q * 4 + 0];
            v.y = acc[r][q * 4 + 1] + bh[q * 4 + 1];
            v.z = acc[r][q * 4 + 2] + bh[q * 4 + 2];
            v.w = acc[r][q * 4 + 3] + bh[q * 4 + 3];
            *reinterpret_cast<float4*>(&embW[orow + q * 4]) = v;
        }
    }
}

// ---------------------------------------------------------------------------
// Kernel B: sequential RNN, W-in-VGPR decomposition.
// 256 blocks x 512 threads (1/CU). Block (bgrp = bid&31, jgrp = bid>>5) owns
//   rows r0..r0+3 (r0 = bgrp*4) x cols j0..j0+63 (j0 = jgrp*64).
// W slice lives in REGISTERS: thread (wave w, lane l) holds wreg[64] =
//   W_hh[w*64 .. w*64+63][j0+l] (R4 lesson: W in LDS made the k-loop
//   LDS-pipe-bound at ~2048 ds-instr/CU/step; now the k-loop's only LDS
//   traffic is 512 broadcast ds_read_b128/CU/step).
// hs layout [r][k]: staging writes are lane-consecutive (conflict-free; the
//   R4 hs[k][r] layout's 16-way write conflict = the 5.9e7 counter).
// Exchange/barrier: byte-identical structure to R4 (relaxed agent-scope
//   atomics + acq_rel per-(bgrp,ts) counter, 8 siblings/group; bgrp=bid&31
//   keeps siblings on one XCD under round-robin placement — perf-only).
// ---------------------------------------------------------------------------
__global__ __launch_bounds__(512, 1) void rnn_kernel(
    const int* __restrict__ inputs, const float* __restrict__ embW,
    const float* __restrict__ W_hh, float* hA, float* hB,
    int* bar)
{
    __shared__ __align__(16) float hs[ROWS_PB * HID];           // [r*512+k] 8 KB
    __shared__ __align__(16) float pb[8][ROWS_PB][COLS_PB];     // 8 KB

    const int t    = threadIdx.x;
    const int w    = t >> 6;          // wave 0..7 = k-octant
    const int l    = t & 63;          // lane = local col
    const int bid  = blockIdx.x;
    const int bgrp = bid & 31;
    const int jgrp = bid >> 5;
    const int j0   = jgrp * COLS_PB;
    const int r0   = bgrp * ROWS_PB;
    const int rc   = t >> 6;          // combine identity (valid for t<256)

    // ---- W slice into registers (one-time; coalesced 256B/row) ----
    float wreg[64];
    {
        const float* wp = W_hh + (size_t)(w * 64) * HID + j0 + l;
        #pragma unroll
        for (int i = 0; i < 64; ++i)
            wreg[i] = wp[(size_t)i * HID];
    }

    const size_t hoff = (size_t)r0 * HID;   // group's 4-row window

    for (int ts = 0; ts < MAXLEN; ++ts) {
        const float* hc = ((ts & 1) ? hB : hA) + hoff;
        float*       hn = (ts & 1) ? hA : hB;

        // ---- stage h (2048 dwords): thread t loads 4, lane-consecutive ----
        #pragma unroll
        for (int q = 0; q < 4; ++q) {
            const float v = __hip_atomic_load(&hc[q * 512 + t],
                                              __ATOMIC_RELAXED,
                                              __HIP_MEMORY_SCOPE_AGENT);
            hs[q * 512 + t] = v;
        }

        // feedforward gather (combine threads only; hides under k-loop)
        float ev = 0.f;
        if (t < 256) {
            const int tok = inputs[(r0 + rc) * MAXLEN + ts];
            ev = embW[(size_t)tok * HID + j0 + l];
        }
        __syncthreads();

        // ---- k-loop: octant w, col l, 4 rows; W from VGPR, h broadcast ----
        float a0 = 0.f, a1 = 0.f, a2 = 0.f, a3 = 0.f;
        float c0 = 0.f, c1 = 0.f, c2 = 0.f, c3 = 0.f;   // ILP split
        const int koff = w * 64;
        #pragma unroll
        for (int i = 0; i < 16; ++i) {
            const int k4 = koff + i * 4;
            const float4 h0 = *(const float4*)&hs[0 * 512 + k4];
            const float4 h1 = *(const float4*)&hs[1 * 512 + k4];
            const float4 h2 = *(const float4*)&hs[2 * 512 + k4];
            const float4 h3 = *(const float4*)&hs[3 * 512 + k4];
            const float w0 = wreg[i * 4 + 0];
            const float w1 = wreg[i * 4 + 1];
            const float w2 = wreg[i * 4 + 2];
            const float w3 = wreg[i * 4 + 3];
            a0 = fmaf(w0, h0.x, a0); c0 = fmaf(w1, h0.y, c0);
            a0 = fmaf(w2, h0.z, a0); c0 = fmaf(w3, h0.w, c0);
            a1 = fmaf(w0, h1.x, a1); c1 = fmaf(w1, h1.y, c1);
            a1 = fmaf(w2, h1.z, a1); c1 = fmaf(w3, h1.w, c1);
            a2 = fmaf(w0, h2.x, a2); c2 = fmaf(w1, h2.y, c2);
            a2 = fmaf(w2, h2.z, a2); c2 = fmaf(w3, h2.w, c2);
            a3 = fmaf(w0, h3.x, a3); c3 = fmaf(w1, h3.y, c3);
            a3 = fmaf(w2, h3.z, a3); c3 = fmaf(w3, h3.w, c3);
        }
        pb[w][0][l] = a0 + c0;
        pb[w][1][l] = a1 + c1;
        pb[w][2][l] = a2 + c2;
        pb[w][3][l] = a3 + c3;
        __syncthreads();

        // ---- combine (threads t<256: row rc, col l), tanh, publish ----
        if (t < 256) {
            float s = ev;
            #pragma unroll
            for (int q = 0; q < 8; ++q) s += pb[q][rc][l];
            s = tanhf(s);
            __hip_atomic_store(&hn[(size_t)(r0 + rc) * HID + j0 + l], s,
                               __ATOMIC_RELAXED, __HIP_MEMORY_SCOPE_AGENT);
        }
        __syncthreads();   // compiler emits vmcnt(0) drain before s_barrier

        // ---- 8-block barrier for this bgrp at this step ----
        if (t == 0) {
            int* c = &bar[bgrp * MAXLEN + ts];
            __hip_atomic_fetch_add(c, 1, __ATOMIC_ACQ_REL,
                                   __HIP_MEMORY_SCOPE_AGENT);
            while (__hip_atomic_load(c, __ATOMIC_ACQUIRE,
                                     __HIP_MEMORY_SCOPE_AGENT) < NB_J) {
                __builtin_amdgcn_s_sleep(2);
            }
        }
        __syncthreads();
    }
    // final h in hA (MAXLEN even)
}

// ---------------------------------------------------------------------------
// Kernel C: logits = hA @ W_out + b_out, sigmoid. Tiny.
// ---------------------------------------------------------------------------
__global__ void head_kernel(const float* __restrict__ h_final,
                            const float* __restrict__ W_out,
                            const float* __restrict__ b_out,
                            float* __restrict__ out)
{
    const int t = threadIdx.x;
    const int b = t >> 1, c = t & 1;
    float acc = b_out[c];
    for (int k = 0; k < HID; ++k)
        acc = fmaf(h_final[(size_t)b * HID + k], W_out[k * NCLASS + c], acc);
    out[t] = 1.f / (1.f + expf(-acc));
}

// ---------------------------------------------------------------------------
extern "C" void kernel_launch(void* const* d_in, const int* in_sizes, int n_in,
                              void* d_out, int out_size, void* d_ws,
                              size_t ws_size, hipStream_t stream)
{
    const int*   inputs = (const int*)  d_in[0];
    const float* emb    = (const float*)d_in[1];
    const float* W_ih   = (const float*)d_in[2];
    const float* W_hh   = (const float*)d_in[3];
    const float* b_h    = (const float*)d_in[4];
    const float* W_out  = (const float*)d_in[5];
    const float* b_out  = (const float*)d_in[6];
    float* out = (float*)d_out;

    // ws layout: embW 64 MB | hA 256 KB | hB 256 KB | bar 64 KB
    float* embW = (float*)d_ws;
    float* hA   = embW + (size_t)VOCAB * HID;
    float* hB   = hA + (size_t)BATCH * HID;
    int*   bar  = (int*)(hB + (size_t)BATCH * HID);

    // per-launch re-init (graph-capture-safe, deterministic)
    hipMemsetAsync(hA, 0, (size_t)BATCH * HID * sizeof(float), stream);
    hipMemsetAsync(bar, 0, (size_t)NB_B * MAXLEN * sizeof(int), stream);

    embw_kernel<<<VOCAB / 64, 256, 0, stream>>>(emb, W_ih, b_h, embW);
    rnn_kernel<<<NB_B * NB_J, 512, 0, stream>>>(inputs, embW, W_hh,
                                                hA, hB, bar);
    head_kernel<<<1, 256, 0, stream>>>(hA, W_out, b_out, out);
}

// Round 7
// 4274.926 us; speedup vs baseline: 1.0000x; 1.0000x over previous
//
#include <hip/hip_runtime.h>
#include <math.h>

#define VOCAB  32000
#define EMB    256
#define HID    512
#define MAXLEN 512
#define BATCH  128
#define NCLASS 2

#define NB_J    8    // column groups (64 cols each)
#define NB_B    32   // batch groups (4 rows each)
#define ROWS_PB 4
#define COLS_PB 64

// ---------------------------------------------------------------------------
// Kernel A: embW[v][j] = b_h[j] + sum_e emb[v][e] * W_ih[e][j]
// (unchanged — ~70 us)
// ---------------------------------------------------------------------------
__global__ __launch_bounds__(256, 1) void embw_kernel(
    const float* __restrict__ emb, const float* __restrict__ W_ih,
    const float* __restrict__ b_h, float* __restrict__ embW)
{
    __shared__ __align__(16) float aT[EMB][64];
    __shared__ __align__(16) float wS[32][HID];

    const int t    = threadIdx.x;
    const int row0 = blockIdx.x * 64;

    {
        const int row   = t >> 2;
        const int elane = t & 3;
        for (int i = 0; i < 16; ++i) {
            const int e = elane * 4 + i * 16;
            const float4 v = *reinterpret_cast<const float4*>(
                &emb[(size_t)(row0 + row) * EMB + e]);
            aT[e + 0][row] = v.x;
            aT[e + 1][row] = v.y;
            aT[e + 2][row] = v.z;
            aT[e + 3][row] = v.w;
        }
    }

    const int rg = t >> 5;
    const int cg = t & 31;

    float acc[8][16];
    #pragma unroll
    for (int r = 0; r < 8; ++r)
        #pragma unroll
        for (int c = 0; c < 16; ++c) acc[r][c] = 0.f;

    for (int ec = 0; ec < 8; ++ec) {
        __syncthreads();
        {
            const int j4  = (t & 127) * 4;
            const int keb = (t >> 7);
            #pragma unroll
            for (int i = 0; i < 16; ++i) {
                const int ke = keb + i * 2;
                const float4 v = *reinterpret_cast<const float4*>(
                    &W_ih[(size_t)(ec * 32 + ke) * HID + j4]);
                *reinterpret_cast<float4*>(&wS[ke][j4]) = v;
            }
        }
        __syncthreads();

        for (int ke = 0; ke < 32; ++ke) {
            float a8[8];
            *(float4*)&a8[0] = *(const float4*)&aT[ec * 32 + ke][rg * 8];
            *(float4*)&a8[4] = *(const float4*)&aT[ec * 32 + ke][rg * 8 + 4];
            float w16[16];
            #pragma unroll
            for (int q = 0; q < 4; ++q)
                *(float4*)&w16[q * 4] =
                    *(const float4*)&wS[ke][cg * 16 + q * 4];
            #pragma unroll
            for (int r = 0; r < 8; ++r)
                #pragma unroll
                for (int c = 0; c < 16; ++c)
                    acc[r][c] = fmaf(a8[r], w16[c], acc[r][c]);
        }
    }

    float bh[16];
    #pragma unroll
    for (int q = 0; q < 4; ++q)
        *(float4*)&bh[q * 4] = *(const float4*)&b_h[cg * 16 + q * 4];
    #pragma unroll
    for (int r = 0; r < 8; ++r) {
        const size_t orow = (size_t)(row0 + rg * 8 + r) * HID + cg * 16;
        #pragma unroll
        for (int q = 0; q < 4; ++q) {
            float4 v;
            v.x = acc[r][q * 4 + 0] + bh[q * 4 + 0];
            v.y = acc[r][q * 4 + 1] + bh[q * 4 + 1];
            v.z = acc[r][q * 4 + 2] + bh[q * 4 + 2];
            v.w = acc[r][q * 4 + 3] + bh[q * 4 + 3];
            *reinterpret_cast<float4*>(&embW[orow + q * 4]) = v;
        }
    }
}

// ---------------------------------------------------------------------------
// Kernel B: sequential RNN, W-in-VGPR decomposition (R5 structure).
// 256 blocks x 512 threads (1/CU). Block (bgrp = bid&31, jgrp = bid>>5) owns
//   rows r0..r0+3 x cols j0..j0+63.
// R5 lesson: without pinning, the compiler SANK the wreg loads back into the
//   ts loop (VGPR_Count=56 proved it) -> 64 L2 loads/thread/step, latency-
//   bound at 8us/step. Fix: asm volatile "+v" makes each wreg value an
//   opaque register definition — not rematerializable, must stay live.
// hs layout [r][k]: lane-consecutive staging writes (R5: BANK_CONFLICT=0).
// Exchange/barrier: R4/R5-proven (relaxed agent atomics + acq_rel counter,
//   8 siblings/bgrp; bgrp=bid&31 => siblings share an XCD round-robin).
// ---------------------------------------------------------------------------
__global__ __launch_bounds__(512, 1) void rnn_kernel(
    const int* __restrict__ inputs, const float* __restrict__ embW,
    const float* __restrict__ W_hh, float* hA, float* hB,
    int* bar)
{
    __shared__ __align__(16) float hs[ROWS_PB * HID];           // 8 KB
    __shared__ __align__(16) float pb[8][ROWS_PB][COLS_PB];     // 8 KB

    const int t    = threadIdx.x;
    const int w    = t >> 6;          // wave 0..7 = k-octant
    const int l    = t & 63;          // lane = local col
    const int bid  = blockIdx.x;
    const int bgrp = bid & 31;
    const int jgrp = bid >> 5;
    const int j0   = jgrp * COLS_PB;
    const int r0   = bgrp * ROWS_PB;
    const int rc   = t >> 6;          // combine identity (valid for t<256)

    // ---- W slice into registers (one-time; coalesced 256B/row) ----
    float wreg[64];
    {
        const float* wp = W_hh + (size_t)(w * 64) * HID + j0 + l;
        #pragma unroll
        for (int i = 0; i < 64; ++i)
            wreg[i] = wp[(size_t)i * HID];
    }
    // Pin: opaque asm definition prevents rematerialization of the loads
    // inside the ts loop. This is the round's single change.
    #pragma unroll
    for (int i = 0; i < 64; ++i)
        asm volatile("" : "+v"(wreg[i]));

    const size_t hoff = (size_t)r0 * HID;   // group's 4-row window

    for (int ts = 0; ts < MAXLEN; ++ts) {
        const float* hc = ((ts & 1) ? hB : hA) + hoff;
        float*       hn = (ts & 1) ? hA : hB;

        // ---- stage h (2048 dwords): thread t loads 4, lane-consecutive ----
        #pragma unroll
        for (int q = 0; q < 4; ++q) {
            const float v = __hip_atomic_load(&hc[q * 512 + t],
                                              __ATOMIC_RELAXED,
                                              __HIP_MEMORY_SCOPE_AGENT);
            hs[q * 512 + t] = v;
        }

        // feedforward gather (combine threads only; hides under k-loop)
        float ev = 0.f;
        if (t < 256) {
            const int tok = inputs[(r0 + rc) * MAXLEN + ts];
            ev = embW[(size_t)tok * HID + j0 + l];
        }
        __syncthreads();

        // ---- k-loop: octant w, col l, 4 rows; W from VGPR, h broadcast ----
        float a0 = 0.f, a1 = 0.f, a2 = 0.f, a3 = 0.f;
        float c0 = 0.f, c1 = 0.f, c2 = 0.f, c3 = 0.f;   // ILP split
        const int koff = w * 64;
        #pragma unroll
        for (int i = 0; i < 16; ++i) {
            const int k4 = koff + i * 4;
            const float4 h0 = *(const float4*)&hs[0 * 512 + k4];
            const float4 h1 = *(const float4*)&hs[1 * 512 + k4];
            const float4 h2 = *(const float4*)&hs[2 * 512 + k4];
            const float4 h3 = *(const float4*)&hs[3 * 512 + k4];
            const float w0 = wreg[i * 4 + 0];
            const float w1 = wreg[i * 4 + 1];
            const float w2 = wreg[i * 4 + 2];
            const float w3 = wreg[i * 4 + 3];
            a0 = fmaf(w0, h0.x, a0); c0 = fmaf(w1, h0.y, c0);
            a0 = fmaf(w2, h0.z, a0); c0 = fmaf(w3, h0.w, c0);
            a1 = fmaf(w0, h1.x, a1); c1 = fmaf(w1, h1.y, c1);
            a1 = fmaf(w2, h1.z, a1); c1 = fmaf(w3, h1.w, c1);
            a2 = fmaf(w0, h2.x, a2); c2 = fmaf(w1, h2.y, c2);
            a2 = fmaf(w2, h2.z, a2); c2 = fmaf(w3, h2.w, c2);
            a3 = fmaf(w0, h3.x, a3); c3 = fmaf(w1, h3.y, c3);
            a3 = fmaf(w2, h3.z, a3); c3 = fmaf(w3, h3.w, c3);
        }
        pb[w][0][l] = a0 + c0;
        pb[w][1][l] = a1 + c1;
        pb[w][2][l] = a2 + c2;
        pb[w][3][l] = a3 + c3;
        __syncthreads();

        // ---- combine (threads t<256: row rc, col l), tanh, publish ----
        if (t < 256) {
            float s = ev;
            #pragma unroll
            for (int q = 0; q < 8; ++q) s += pb[q][rc][l];
            s = tanhf(s);
            __hip_atomic_store(&hn[(size_t)(r0 + rc) * HID + j0 + l], s,
                               __ATOMIC_RELAXED, __HIP_MEMORY_SCOPE_AGENT);
        }
        __syncthreads();   // drains vmcnt: all stores complete before barrier

        // ---- 8-block barrier for this bgrp at this step ----
        if (t == 0) {
            int* c = &bar[bgrp * MAXLEN + ts];
            __hip_atomic_fetch_add(c, 1, __ATOMIC_ACQ_REL,
                                   __HIP_MEMORY_SCOPE_AGENT);
            while (__hip_atomic_load(c, __ATOMIC_ACQUIRE,
                                     __HIP_MEMORY_SCOPE_AGENT) < NB_J) {
                __builtin_amdgcn_s_sleep(1);
            }
        }
        __syncthreads();
    }
    // final h in hA (MAXLEN even)
}

// ---------------------------------------------------------------------------
// Kernel C: logits = hA @ W_out + b_out, sigmoid. Tiny.
// ---------------------------------------------------------------------------
__global__ void head_kernel(const float* __restrict__ h_final,
                            const float* __restrict__ W_out,
                            const float* __restrict__ b_out,
                            float* __restrict__ out)
{
    const int t = threadIdx.x;
    const int b = t >> 1, c = t & 1;
    float acc = b_out[c];
    for (int k = 0; k < HID; ++k)
        acc = fmaf(h_final[(size_t)b * HID + k], W_out[k * NCLASS + c], acc);
    out[t] = 1.f / (1.f + expf(-acc));
}

// ---------------------------------------------------------------------------
extern "C" void kernel_launch(void* const* d_in, const int* in_sizes, int n_in,
                              void* d_out, int out_size, void* d_ws,
                              size_t ws_size, hipStream_t stream)
{
    const int*   inputs = (const int*)  d_in[0];
    const float* emb    = (const float*)d_in[1];
    const float* W_ih   = (const float*)d_in[2];
    const float* W_hh   = (const float*)d_in[3];
    const float* b_h    = (const float*)d_in[4];
    const float* W_out  = (const float*)d_in[5];
    const float* b_out  = (const float*)d_in[6];
    float* out = (float*)d_out;

    // ws layout: embW 64 MB | hA 256 KB | hB 256 KB | bar 64 KB
    float* embW = (float*)d_ws;
    float* hA   = embW + (size_t)VOCAB * HID;
    float* hB   = hA + (size_t)BATCH * HID;
    int*   bar  = (int*)(hB + (size_t)BATCH * HID);

    // per-launch re-init (graph-capture-safe, deterministic)
    hipMemsetAsync(hA, 0, (size_t)BATCH * HID * sizeof(float), stream);
    hipMemsetAsync(bar, 0, (size_t)NB_B * MAXLEN * sizeof(int), stream);

    embw_kernel<<<VOCAB / 64, 256, 0, stream>>>(emb, W_ih, b_h, embW);
    rnn_kernel<<<NB_B * NB_J, 512, 0, stream>>>(inputs, embW, W_hh,
                                                hA, hB, bar);
    head_kernel<<<1, 256, 0, stream>>>(hA, W_out, b_out, out);
}